// Round 8
// baseline (163.987 us; speedup 1.0000x reference)
//
#include <hip/hip_runtime.h>
#include <math.h>

#define NH 16
#define HD 64
#define SEQ 2048
#define BAT 2
#define EMB 1024
#define MTOT (BAT*SEQ)   // 4096
#define NTOT (3*EMB)     // 3072

typedef __attribute__((ext_vector_type(8))) short bf16x8;
typedef __attribute__((ext_vector_type(4))) float f32x4;

#define MFMA16(a,b,c) __builtin_amdgcn_mfma_f32_16x16x32_bf16(a,b,c,0,0,0)

__device__ inline short f2bf(float f) {
    union { float f; unsigned u; } x; x.f = f;
    unsigned r = (x.u + 0x7FFF + ((x.u >> 16) & 1)) >> 16;
    return (short)r;
}

// raw v_exp_f32 (inputs bounded to [-12,12]: no range/denorm handling needed)
__device__ inline float fast_exp2(float x) {
#if __has_builtin(__builtin_amdgcn_exp2f)
    return __builtin_amdgcn_exp2f(x);
#else
    float r; asm("v_exp_f32 %0, %1" : "=v"(r) : "v"(x)); return r;
#endif
}

// pack two f32 -> bf16x2 by TRUNCATION: single v_perm (P-weights; bias
// cancels in O/l ratio since l uses the same truncated P)
__device__ inline unsigned pack2bf_t(float a, float b) {
    union { float f; unsigned u; } x, y; x.f = a; y.f = b;
    return __builtin_amdgcn_perm(y.u, x.u, 0x07060302u);
}

typedef const __attribute__((address_space(1))) void* gp_t;
typedef __attribute__((address_space(3))) void* lp_t;
// async global->LDS, 16B/lane; LDS dest = wave-uniform base + lane*16
__device__ inline void gload16(const void* g, void* l) {
    __builtin_amdgcn_global_load_lds((gp_t)(uintptr_t)g, (lp_t)(uintptr_t)l, 16, 0, 0);
}

// raw barrier (no vmcnt drain) + counted vmcnt waits
#define BARR() asm volatile("s_barrier" ::: "memory")
#define VMW(N) asm volatile("s_waitcnt vmcnt(" #N ")" ::: "memory")

// ---------------------------------------------------------------------------
// Prep: f32 -> bf16 for X (4M) and Wq|Wk|Wv (3M) into scratch carved from d_out.
// ---------------------------------------------------------------------------
__global__ __launch_bounds__(256) void prep_kernel(
    const float* __restrict__ x, const float* __restrict__ wq,
    const float* __restrict__ wk, const float* __restrict__ wv,
    short* __restrict__ xb, short* __restrict__ wb)
{
    const size_t NX = (size_t)MTOT * EMB;
    const size_t NW = (size_t)EMB * EMB;
    const size_t i4 = ((size_t)blockIdx.x * 256 + threadIdx.x) * 4;
    float4 v; short* dst;
    if (i4 < NX) { v = *(const float4*)(x + i4); dst = xb + i4; }
    else {
        size_t j = i4 - NX;
        const float* s = (j < NW) ? wq : (j < 2 * NW) ? wk : wv;
        v = *(const float4*)(s + (j & (NW - 1)));
        dst = wb + j;
    }
    short4 o; o.x = f2bf(v.x); o.y = f2bf(v.y); o.z = f2bf(v.z); o.w = f2bf(v.w);
    *(short4*)dst = o;
}

// ---------------------------------------------------------------------------
// Fused QKV GEMM: FROZEN from R7 (measured 44.0 us, best).
// 128x128 tile, BK=32, tri-buffered depth-2 prefetch, counted vmcnt.
// Ledger (per-wave, stageg = 4 gload16): prologue t0,t1 -> VMW(4) retires t0;
// iter it issues t_{it+2}, VMW(4) at end retires t_{it+1}, t_{it+2} rides
// across the raw barrier. LDS 48 KB -> 3 blocks/CU. Now near LDS-BW-bound
// (per CU-iter: MFMA ~930cyc, ds_read ~1150, lds-writes ~770).
// ---------------------------------------------------------------------------
__global__ __launch_bounds__(256, 3) void qkv_gemm_fast(
    const short* __restrict__ xb, const short* __restrict__ wb,
    short* __restrict__ qws, short* __restrict__ kws, short* __restrict__ vperm,
    const float* __restrict__ gptr)
{
    __shared__ short smem[3 * 2 * 128 * 32];   // 3 bufs x (8KB A + 8KB B) = 48 KB; T reuse
    const int m0 = blockIdx.x * 128, n0 = blockIdx.y * 128;
    const int t = threadIdx.x, wave = t >> 6, lane = t & 63;
    const int quad = lane >> 4, l16 = lane & 15;
    const int wm = (wave & 1) * 64, wn = (wave >> 1) * 64;

    // staging decode: instr j covers rows wave*32 + j*16 + (lane>>2)
    const int srow = wave * 32 + (lane >> 2);
    const int scol = ((lane & 3) ^ ((lane >> 3) & 3)) * 8;   // pre-swizzled source granule
    const short* ga = xb + (size_t)(m0 + srow) * EMB + scol;
    const short* gb = wb + (size_t)(n0 + srow) * EMB + scol;

    // frag read offsets (buffer-relative, shorts); swizzle: granule ^ ((row>>1)&3)
    const int swz = (quad ^ ((l16 >> 1) & 3)) * 8;
    int aoff[4], boff[4];
#pragma unroll
    for (int mf = 0; mf < 4; ++mf) aoff[mf] = (wm + mf * 16 + l16) * 32 + swz;
#pragma unroll
    for (int nf = 0; nf < 4; ++nf) boff[nf] = 4096 + (wn + nf * 16 + l16) * 32 + swz;

    f32x4 acc[4][4] = {};

    // stage K-step k0 into buffer p (8 KB A + 8 KB B); 4 gload16 per wave
    auto stageg = [&](int k0, int p) {
        short* lA = smem + p * 8192 + wave * 1024;
        short* lB = smem + p * 8192 + 4096 + wave * 1024;
#pragma unroll
        for (int j = 0; j < 2; ++j) {
            gload16(ga + k0 + (size_t)j * 16 * EMB, lA + j * 512);
            gload16(gb + k0 + (size_t)j * 16 * EMB, lB + j * 512);
        }
    };

    // prologue: t0 -> buf0, t1 -> buf1; retire t0 only (t1 stays in flight)
    stageg(0, 0);
    stageg(32, 1);
    VMW(4);
    BARR();

    int p = 0, pn = 2;   // compute buffer / next stage buffer
#pragma unroll 1
    for (int it = 0; it < EMB / 32; ++it) {
        if (it + 2 < EMB / 32) stageg((it + 2) * 32, pn);
        const short* base = smem + p * 8192;
        bf16x8 af[4], bfr[4];
#pragma unroll
        for (int i = 0; i < 4; ++i) af[i]  = *(const bf16x8*)(base + aoff[i]);
#pragma unroll
        for (int i = 0; i < 4; ++i) bfr[i] = *(const bf16x8*)(base + boff[i]);
#pragma unroll
        for (int mf = 0; mf < 4; ++mf)
#pragma unroll
            for (int nf = 0; nf < 4; ++nf)
                acc[mf][nf] = MFMA16(af[mf], bfr[nf], acc[mf][nf]);
        if (it + 2 < EMB / 32) { VMW(4); }   // retire t_{it+1}; t_{it+2} in flight
        else                   { VMW(0); }   // tail: drain
        BARR();
        p  = (p  == 2) ? 0 : p  + 1;
        pn = (pn == 2) ? 0 : pn + 1;
    }

    // ---- epilogue (through LDS, coalesced stores) ----
    short* T = smem;   // 128 rows x 128 cols bf16, 16B-granule XOR swizzle
    const int mat = n0 >> 10;   // 0=Q,1=K,2=V (block-uniform)

    if (mat < 2) {
        const float scale = (mat == 0) ? gptr[0] * 1.4426950408889634f : 1.0f;
        float inv[4][4];
#pragma unroll
        for (int mf = 0; mf < 4; ++mf)
#pragma unroll
            for (int reg = 0; reg < 4; ++reg) {
                float ss = 0.f;
#pragma unroll
                for (int nf = 0; nf < 4; ++nf) { float v = acc[mf][nf][reg]; ss += v * v; }
                ss += __shfl_xor(ss, 1, 16);
                ss += __shfl_xor(ss, 2, 16);
                ss += __shfl_xor(ss, 4, 16);
                ss += __shfl_xor(ss, 8, 16);
                inv[mf][reg] = scale / fmaxf(sqrtf(ss), 1e-12f);
            }
#pragma unroll
        for (int mf = 0; mf < 4; ++mf)
#pragma unroll
            for (int nf = 0; nf < 4; ++nf) {
                const int c = wn + nf * 16 + l16;
#pragma unroll
                for (int reg = 0; reg < 4; ++reg) {
                    const int s = wm + mf * 16 + quad * 4 + reg;
                    T[s * 128 + (((c >> 3) ^ (s & 15)) << 3) + (c & 7)] =
                        f2bf(acc[mf][nf][reg] * inv[mf][reg]);
                }
            }
        __syncthreads();
        short* outp = (mat == 0) ? qws : kws;
        const int r = t >> 1, half = t & 1;
        const int sg = m0 + r, bb = sg >> 11, sl = sg & (SEQ - 1);
        const int h = ((n0 & 1023) >> 6) + half;
        short* orow = outp + ((size_t)(bb * NH + h) * SEQ + sl) * HD;
#pragma unroll
        for (int j = 0; j < 8; ++j) {
            int4 v = *(const int4*)&T[r * 128 + ((((half * 8 + j)) ^ (r & 15)) << 3)];
            *(int4*)&orow[j * 8] = v;
        }
    } else {
        // V: write rows at pos-permuted s, read transposed, store contiguous
#pragma unroll
        for (int mf = 0; mf < 4; ++mf)
#pragma unroll
            for (int nf = 0; nf < 4; ++nf) {
                const int c = wn + nf * 16 + l16;
#pragma unroll
                for (int reg = 0; reg < 4; ++reg) {
                    const int s = wm + mf * 16 + quad * 4 + reg;
                    const int sp = (s & ~31) + ((s & 12) >> 2) * 8 + ((s >> 4) & 1) * 4 + (s & 3);
                    T[sp * 128 + (((c >> 3) ^ (sp & 15)) << 3) + (c & 7)] =
                        f2bf(acc[mf][nf][reg]);
                }
            }
        __syncthreads();
        const int c = t >> 1, half = t & 1;
        const int h = ((n0 & 1023) >> 6) + (c >> 6), d = c & 63;
        const int bb = m0 >> 11, p0 = (m0 & (SEQ - 1)) + half * 64;
        short* vrow = vperm + ((size_t)(bb * NH + h) * HD + d) * SEQ + p0;
        const int cg = c >> 3, ce = c & 7;
#pragma unroll
        for (int j = 0; j < 8; ++j) {
            union { int4 v; short s[8]; } tmp;
#pragma unroll
            for (int e = 0; e < 8; ++e) {
                const int s = half * 64 + j * 8 + e;
                tmp.s[e] = T[s * 128 + ((cg ^ (s & 15)) << 3) + ce];
            }
            *(int4*)&vrow[j * 8] = tmp.v;
        }
    }
}

// ---------------------------------------------------------------------------
// Attention v1 + R7's validated pipeline technique: TRI-buffered K/V tiles
// with counted vmcnt + raw barriers (replaces dbuf + __syncthreads whose
// vmcnt(0) drain serialized every tile), and incremental staging pointers
// (kills the per-tile row*HD mul chains -- part of the 43.5% VALUBusy).
// Ledger (per-wave stage = 4 gload16, both K- and V-roles): prologue t0,t1
// -> VMW(4) retires t0; iter tt issues t_{tt+2} into buf (tt+2)%3, VMW(4)
// at end retires t_{tt+1}; t_{tt+2} rides across the barrier; tails VMW(0).
// WAR on buf (tt+2)%3: last read at iter tt-1, guarded by its closing
// barrier. Compute path bit-identical to the measured v1.
// LDS 3x16KB + lbuf = 48.3 KB -> 3 blocks/CU (12 waves, was 16).
// red reduction buffer: Kt is now 24 KB >= 16 KB needed.
// ---------------------------------------------------------------------------
__global__ __launch_bounds__(256, 3) void attn_kernel(
    const short* __restrict__ qws, const short* __restrict__ kws,
    const short* __restrict__ vperm, float* __restrict__ out)
{
    __shared__ short Kt[3][2][2048];   // [buf][kh][klocal*64 + dgrp_phys*8]
    __shared__ short Vt[3][2][2048];   // [buf][kh][d*32 + ug_phys*8]
    __shared__ float lbuf[64];

    const int id = blockIdx.x;
    const int bh = (id & 7) * 4 + ((id >> 3) & 3);
    const int qt = id >> 5;                        // 0..31
    const int b = bh >> 4, h = bh & (NH - 1);
    const size_t base = (size_t)bh * SEQ * HD;
    const int t = threadIdx.x, wave = t >> 6, lane = t & 63;
    const int quad = lane >> 4, l16 = lane & 15;
    const int qh = wave >> 1, kh = wave & 1;

    // Q B-frags (q = qt*64 + qh*32 + qsub*16 + l16), loaded once
    bf16x8 bq[2][2];
#pragma unroll
    for (int qsub = 0; qsub < 2; ++qsub) {
        const short* qp = qws + base +
            (size_t)(qt * 64 + qh * 32 + qsub * 16 + l16) * HD + quad * 8;
        bq[qsub][0] = *(const bf16x8*)(qp);
        bq[qsub][1] = *(const bf16x8*)(qp + 32);
    }
    bf16x8 ones;
#pragma unroll
    for (int i = 0; i < 8; ++i) ones[i] = (short)0x3F80;

    // frag read offsets (shorts, within this wave's kh region)
    int koff[2][2];   // [msub][ks]: K A-frag, key=msub*16+l16, d=ks*32+quad*8
#pragma unroll
    for (int msub = 0; msub < 2; ++msub)
#pragma unroll
        for (int ks = 0; ks < 2; ++ks)
            koff[msub][ks] = (msub * 16 + l16) * 64 + (((ks * 4 + quad) ^ (l16 & 7)) * 8);
    int voff[4];      // V B-frag: d=nt*16+l16, slot group = quad (phys ^ (d>>1)&3)
#pragma unroll
    for (int nt = 0; nt < 4; ++nt) {
        const int d = nt * 16 + l16;
        voff[nt] = d * 32 + ((quad ^ ((d >> 1) & 3)) * 8);
    }

    f32x4 o_acc[2][4] = {};   // [qsub][nt]
    f32x4 l_acc[2] = {};

    // full-compute staging (prologue only)
    auto stage0 = [&](int tt, int p) {
        if (qh == 0) {  // K strip: [32 keys][64 d], 4 gload16
#pragma unroll
            for (int j = 0; j < 4; ++j) {
                const int kl = j * 8 + (lane >> 3);
                const int row = tt * 64 + kh * 32 + kl;
                gload16(kws + base + (size_t)row * HD + (((lane & 7) ^ (kl & 7)) * 8),
                        &Kt[p][kh][j * 512 + lane * 8]);
            }
        } else {        // V strip: [64 d][32 slots], 4 gload16
#pragma unroll
            for (int j = 0; j < 4; ++j) {
                const int d = j * 16 + (lane >> 2);
                const int ug = (lane & 3) ^ ((d >> 1) & 3);
                gload16(vperm + base + (size_t)d * SEQ + tt * 64 + kh * 32 + ug * 8,
                        &Vt[p][kh][j * 512 + lane * 8]);
            }
        }
    };

    // prologue: t0 -> buf0, t1 -> buf1; retire t0 only (t1 stays in flight)
    stage0(0, 0);
    stage0(1, 1);
    VMW(4);
    BARR();

    // incremental staging pointers, targeting tile 2 (first in-loop stage)
    const short* sp[4];
    int sstep;
    if (qh == 0) {
        sstep = 64 * HD;   // +4096 shorts per tile
#pragma unroll
        for (int j = 0; j < 4; ++j) {
            const int kl = j * 8 + (lane >> 3);
            sp[j] = kws + base + (size_t)(128 + kh * 32 + kl) * HD +
                    (((lane & 7) ^ (kl & 7)) * 8);
        }
    } else {
        sstep = 64;        // +64 shorts per tile
#pragma unroll
        for (int j = 0; j < 4; ++j) {
            const int d = j * 16 + (lane >> 2);
            const int ug = (lane & 3) ^ ((d >> 1) & 3);
            sp[j] = vperm + base + (size_t)d * SEQ + 128 + kh * 32 + ug * 8;
        }
    }

    int p = 0, pn = 2;   // compute buffer / next stage buffer
#pragma unroll 1
    for (int tt = 0; tt < SEQ / 64; ++tt) {
        if (tt + 2 < SEQ / 64) {
            if (qh == 0) {
#pragma unroll
                for (int j = 0; j < 4; ++j) {
                    gload16(sp[j], &Kt[pn][kh][j * 512 + lane * 8]);
                    sp[j] += sstep;
                }
            } else {
#pragma unroll
                for (int j = 0; j < 4; ++j) {
                    gload16(sp[j], &Vt[pn][kh][j * 512 + lane * 8]);
                    sp[j] += sstep;
                }
            }
        }
        const short* Kp = &Kt[p][kh][0];
        const short* Vp = &Vt[p][kh][0];

        // S^T: 32 keys (this strip) x 32 q (this half)
        f32x4 st[2][2];   // [msub][qsub]
#pragma unroll
        for (int msub = 0; msub < 2; ++msub) {
            bf16x8 a0 = *(const bf16x8*)(Kp + koff[msub][0]);
            bf16x8 a1 = *(const bf16x8*)(Kp + koff[msub][1]);
#pragma unroll
            for (int qsub = 0; qsub < 2; ++qsub) {
                f32x4 z = {};
                z = MFMA16(a0, bq[qsub][0], z);
                st[msub][qsub] = MFMA16(a1, bq[qsub][1], z);
            }
        }
        // V B-frags (shared across qsub)
        bf16x8 vf[4];
#pragma unroll
        for (int nt = 0; nt < 4; ++nt)
            vf[nt] = *(const bf16x8*)(Vp + voff[nt]);
        // exp + truncating pack -> P A-frag; l + O MFMAs
#pragma unroll
        for (int qsub = 0; qsub < 2; ++qsub) {
            bf16x8 pa;
            unsigned* pu = (unsigned*)&pa;
            pu[0] = pack2bf_t(fast_exp2(st[0][qsub][0]), fast_exp2(st[0][qsub][1]));
            pu[1] = pack2bf_t(fast_exp2(st[0][qsub][2]), fast_exp2(st[0][qsub][3]));
            pu[2] = pack2bf_t(fast_exp2(st[1][qsub][0]), fast_exp2(st[1][qsub][1]));
            pu[3] = pack2bf_t(fast_exp2(st[1][qsub][2]), fast_exp2(st[1][qsub][3]));
            l_acc[qsub] = MFMA16(pa, ones, l_acc[qsub]);
#pragma unroll
            for (int nt = 0; nt < 4; ++nt)
                o_acc[qsub][nt] = MFMA16(pa, vf[nt], o_acc[qsub][nt]);
        }
        if (tt + 2 < SEQ / 64) { VMW(4); }   // retire t_{tt+1}; t_{tt+2} in flight
        else                   { VMW(0); }   // tail: drain
        BARR();
        p  = (p  == 2) ? 0 : p  + 1;
        pn = (pn == 2) ? 0 : pn + 1;
    }

    // ---- cross-kh reduction (reuse Kt as 16 KB float buffer) ----
    float* red = (float*)&Kt[0][0][0];   // [qh][q_local 32][d 64]
    if (kh == 1) {
#pragma unroll
        for (int qsub = 0; qsub < 2; ++qsub) {
#pragma unroll
            for (int nt = 0; nt < 4; ++nt)
#pragma unroll
                for (int r = 0; r < 4; ++r)
                    red[qh * 2048 + (qsub * 16 + quad * 4 + r) * 64 + nt * 16 + l16] =
                        o_acc[qsub][nt][r];
            if (l16 == 0)
#pragma unroll
                for (int r = 0; r < 4; ++r)
                    lbuf[qh * 32 + qsub * 16 + quad * 4 + r] = l_acc[qsub][r];
        }
    }
    __syncthreads();
    if (kh == 0) {
#pragma unroll
        for (int qsub = 0; qsub < 2; ++qsub) {
            float linv[4];
#pragma unroll
            for (int r = 0; r < 4; ++r)
                linv[r] = 1.0f / (l_acc[qsub][r] + lbuf[qh * 32 + qsub * 16 + quad * 4 + r]);
            const int s = qt * 64 + qh * 32 + qsub * 16 + quad * 4;
            float* ob = out + ((size_t)b * SEQ + s) * EMB + h * HD + l16;
#pragma unroll
            for (int nt = 0; nt < 4; ++nt)
#pragma unroll
                for (int r = 0; r < 4; ++r) {
                    const float o = o_acc[qsub][nt][r] +
                        red[qh * 2048 + (qsub * 16 + quad * 4 + r) * 64 + nt * 16 + l16];
                    ob[(size_t)r * EMB + nt * 16] = o * linv[r];
                }
        }
    }
}

extern "C" void kernel_launch(void* const* d_in, const int* in_sizes, int n_in,
                              void* d_out, int out_size, void* d_ws, size_t ws_size,
                              hipStream_t stream) {
    (void)in_sizes; (void)n_in; (void)out_size; (void)ws_size;
    const float* x  = (const float*)d_in[0];
    const float* Wq = (const float*)d_in[1];
    const float* Wk = (const float*)d_in[2];
    const float* Wv = (const float*)d_in[3];
    const float* g  = (const float*)d_in[4];
    float* out = (float*)d_out;

    const size_t per = (size_t)BAT * NH * SEQ * HD;   // 4,194,304 elems
    short* qws   = (short*)d_ws;
    short* kws   = qws + per;
    short* vperm = kws + per;                          // ws: 25.2 MB total

    // bf16 staging lives in d_out (16.8 MB; attn fully overwrites it last)
    short* xb = (short*)out;                           // 4M shorts
    short* wb = xb + (size_t)MTOT * EMB;               // 3M shorts (7M <= 8.38M cap)

    prep_kernel<<<7168, 256, 0, stream>>>(x, Wq, Wk, Wv, xb, wb);
    qkv_gemm_fast<<<dim3(MTOT / 128, NTOT / 128), 256, 0, stream>>>(
        xb, wb, qws, kws, vperm, g);
    attn_kernel<<<(SEQ / 64) * BAT * NH, 256, 0, stream>>>(qws, kws, vperm, out);
}

// Round 9
// 156.485 us; speedup vs baseline: 1.0479x; 1.0479x over previous
//
#include <hip/hip_runtime.h>
#include <math.h>

#define NH 16
#define HD 64
#define SEQ 2048
#define BAT 2
#define EMB 1024
#define MTOT (BAT*SEQ)   // 4096
#define NTOT (3*EMB)     // 3072

typedef __attribute__((ext_vector_type(8))) short bf16x8;
typedef __attribute__((ext_vector_type(4))) float f32x4;

#define MFMA16(a,b,c) __builtin_amdgcn_mfma_f32_16x16x32_bf16(a,b,c,0,0,0)

__device__ inline short f2bf(float f) {
    union { float f; unsigned u; } x; x.f = f;
    unsigned r = (x.u + 0x7FFF + ((x.u >> 16) & 1)) >> 16;
    return (short)r;
}

// raw v_exp_f32 (inputs bounded to [-12,12]: no range/denorm handling needed)
__device__ inline float fast_exp2(float x) {
#if __has_builtin(__builtin_amdgcn_exp2f)
    return __builtin_amdgcn_exp2f(x);
#else
    float r; asm("v_exp_f32 %0, %1" : "=v"(r) : "v"(x)); return r;
#endif
}

// pack two f32 -> bf16x2 by TRUNCATION: single v_perm (P-weights; bias
// cancels in O/l ratio since l uses the same truncated P)
__device__ inline unsigned pack2bf_t(float a, float b) {
    union { float f; unsigned u; } x, y; x.f = a; y.f = b;
    return __builtin_amdgcn_perm(y.u, x.u, 0x07060302u);
}

typedef const __attribute__((address_space(1))) void* gp_t;
typedef __attribute__((address_space(3))) void* lp_t;
// async global->LDS, 16B/lane; LDS dest = wave-uniform base + lane*16
__device__ inline void gload16(const void* g, void* l) {
    __builtin_amdgcn_global_load_lds((gp_t)(uintptr_t)g, (lp_t)(uintptr_t)l, 16, 0, 0);
}

// raw barrier (no vmcnt drain) + counted vmcnt waits
#define BARR() asm volatile("s_barrier" ::: "memory")
#define VMW(N) asm volatile("s_waitcnt vmcnt(" #N ")" ::: "memory")

// ---------------------------------------------------------------------------
// Prep: f32 -> bf16 for X (4M) and Wq|Wk|Wv (3M) into scratch carved from d_out.
// ---------------------------------------------------------------------------
__global__ __launch_bounds__(256) void prep_kernel(
    const float* __restrict__ x, const float* __restrict__ wq,
    const float* __restrict__ wk, const float* __restrict__ wv,
    short* __restrict__ xb, short* __restrict__ wb)
{
    const size_t NX = (size_t)MTOT * EMB;
    const size_t NW = (size_t)EMB * EMB;
    const size_t i4 = ((size_t)blockIdx.x * 256 + threadIdx.x) * 4;
    float4 v; short* dst;
    if (i4 < NX) { v = *(const float4*)(x + i4); dst = xb + i4; }
    else {
        size_t j = i4 - NX;
        const float* s = (j < NW) ? wq : (j < 2 * NW) ? wk : wv;
        v = *(const float4*)(s + (j & (NW - 1)));
        dst = wb + j;
    }
    short4 o; o.x = f2bf(v.x); o.y = f2bf(v.y); o.z = f2bf(v.z); o.w = f2bf(v.w);
    *(short4*)dst = o;
}

// ---------------------------------------------------------------------------
// Fused QKV GEMM: FROZEN from R7 (measured 44.0 us, best).
// 128x128 tile, BK=32, tri-buffered depth-2 prefetch, counted vmcnt.
// Ledger (per-wave, stageg = 4 gload16): prologue t0,t1 -> VMW(4) retires t0;
// iter it issues t_{it+2}, VMW(4) at end retires t_{it+1}, t_{it+2} rides
// across the raw barrier. LDS 48 KB -> 3 blocks/CU. Near LDS-BW-bound.
// ---------------------------------------------------------------------------
__global__ __launch_bounds__(256, 3) void qkv_gemm_fast(
    const short* __restrict__ xb, const short* __restrict__ wb,
    short* __restrict__ qws, short* __restrict__ kws, short* __restrict__ vperm,
    const float* __restrict__ gptr)
{
    __shared__ short smem[3 * 2 * 128 * 32];   // 3 bufs x (8KB A + 8KB B) = 48 KB; T reuse
    const int m0 = blockIdx.x * 128, n0 = blockIdx.y * 128;
    const int t = threadIdx.x, wave = t >> 6, lane = t & 63;
    const int quad = lane >> 4, l16 = lane & 15;
    const int wm = (wave & 1) * 64, wn = (wave >> 1) * 64;

    // staging decode: instr j covers rows wave*32 + j*16 + (lane>>2)
    const int srow = wave * 32 + (lane >> 2);
    const int scol = ((lane & 3) ^ ((lane >> 3) & 3)) * 8;   // pre-swizzled source granule
    const short* ga = xb + (size_t)(m0 + srow) * EMB + scol;
    const short* gb = wb + (size_t)(n0 + srow) * EMB + scol;

    // frag read offsets (buffer-relative, shorts); swizzle: granule ^ ((row>>1)&3)
    const int swz = (quad ^ ((l16 >> 1) & 3)) * 8;
    int aoff[4], boff[4];
#pragma unroll
    for (int mf = 0; mf < 4; ++mf) aoff[mf] = (wm + mf * 16 + l16) * 32 + swz;
#pragma unroll
    for (int nf = 0; nf < 4; ++nf) boff[nf] = 4096 + (wn + nf * 16 + l16) * 32 + swz;

    f32x4 acc[4][4] = {};

    // stage K-step k0 into buffer p (8 KB A + 8 KB B); 4 gload16 per wave
    auto stageg = [&](int k0, int p) {
        short* lA = smem + p * 8192 + wave * 1024;
        short* lB = smem + p * 8192 + 4096 + wave * 1024;
#pragma unroll
        for (int j = 0; j < 2; ++j) {
            gload16(ga + k0 + (size_t)j * 16 * EMB, lA + j * 512);
            gload16(gb + k0 + (size_t)j * 16 * EMB, lB + j * 512);
        }
    };

    // prologue: t0 -> buf0, t1 -> buf1; retire t0 only (t1 stays in flight)
    stageg(0, 0);
    stageg(32, 1);
    VMW(4);
    BARR();

    int p = 0, pn = 2;   // compute buffer / next stage buffer
#pragma unroll 1
    for (int it = 0; it < EMB / 32; ++it) {
        if (it + 2 < EMB / 32) stageg((it + 2) * 32, pn);
        const short* base = smem + p * 8192;
        bf16x8 af[4], bfr[4];
#pragma unroll
        for (int i = 0; i < 4; ++i) af[i]  = *(const bf16x8*)(base + aoff[i]);
#pragma unroll
        for (int i = 0; i < 4; ++i) bfr[i] = *(const bf16x8*)(base + boff[i]);
#pragma unroll
        for (int mf = 0; mf < 4; ++mf)
#pragma unroll
            for (int nf = 0; nf < 4; ++nf)
                acc[mf][nf] = MFMA16(af[mf], bfr[nf], acc[mf][nf]);
        if (it + 2 < EMB / 32) { VMW(4); }   // retire t_{it+1}; t_{it+2} in flight
        else                   { VMW(0); }   // tail: drain
        BARR();
        p  = (p  == 2) ? 0 : p  + 1;
        pn = (pn == 2) ? 0 : pn + 1;
    }

    // ---- epilogue (through LDS, coalesced stores) ----
    short* T = smem;   // 128 rows x 128 cols bf16, 16B-granule XOR swizzle
    const int mat = n0 >> 10;   // 0=Q,1=K,2=V (block-uniform)

    if (mat < 2) {
        const float scale = (mat == 0) ? gptr[0] * 1.4426950408889634f : 1.0f;
        float inv[4][4];
#pragma unroll
        for (int mf = 0; mf < 4; ++mf)
#pragma unroll
            for (int reg = 0; reg < 4; ++reg) {
                float ss = 0.f;
#pragma unroll
                for (int nf = 0; nf < 4; ++nf) { float v = acc[mf][nf][reg]; ss += v * v; }
                ss += __shfl_xor(ss, 1, 16);
                ss += __shfl_xor(ss, 2, 16);
                ss += __shfl_xor(ss, 4, 16);
                ss += __shfl_xor(ss, 8, 16);
                inv[mf][reg] = scale / fmaxf(sqrtf(ss), 1e-12f);
            }
#pragma unroll
        for (int mf = 0; mf < 4; ++mf)
#pragma unroll
            for (int nf = 0; nf < 4; ++nf) {
                const int c = wn + nf * 16 + l16;
#pragma unroll
                for (int reg = 0; reg < 4; ++reg) {
                    const int s = wm + mf * 16 + quad * 4 + reg;
                    T[s * 128 + (((c >> 3) ^ (s & 15)) << 3) + (c & 7)] =
                        f2bf(acc[mf][nf][reg] * inv[mf][reg]);
                }
            }
        __syncthreads();
        short* outp = (mat == 0) ? qws : kws;
        const int r = t >> 1, half = t & 1;
        const int sg = m0 + r, bb = sg >> 11, sl = sg & (SEQ - 1);
        const int h = ((n0 & 1023) >> 6) + half;
        short* orow = outp + ((size_t)(bb * NH + h) * SEQ + sl) * HD;
#pragma unroll
        for (int j = 0; j < 8; ++j) {
            int4 v = *(const int4*)&T[r * 128 + ((((half * 8 + j)) ^ (r & 15)) << 3)];
            *(int4*)&orow[j * 8] = v;
        }
    } else {
        // V: write rows at pos-permuted s, read transposed, store contiguous
#pragma unroll
        for (int mf = 0; mf < 4; ++mf)
#pragma unroll
            for (int nf = 0; nf < 4; ++nf) {
                const int c = wn + nf * 16 + l16;
#pragma unroll
                for (int reg = 0; reg < 4; ++reg) {
                    const int s = wm + mf * 16 + quad * 4 + reg;
                    const int sp = (s & ~31) + ((s & 12) >> 2) * 8 + ((s >> 4) & 1) * 4 + (s & 3);
                    T[sp * 128 + (((c >> 3) ^ (sp & 15)) << 3) + (c & 7)] =
                        f2bf(acc[mf][nf][reg]);
                }
            }
        __syncthreads();
        const int c = t >> 1, half = t & 1;
        const int h = ((n0 & 1023) >> 6) + (c >> 6), d = c & 63;
        const int bb = m0 >> 11, p0 = (m0 & (SEQ - 1)) + half * 64;
        short* vrow = vperm + ((size_t)(bb * NH + h) * HD + d) * SEQ + p0;
        const int cg = c >> 3, ce = c & 7;
#pragma unroll
        for (int j = 0; j < 8; ++j) {
            union { int4 v; short s[8]; } tmp;
#pragma unroll
            for (int e = 0; e < 8; ++e) {
                const int s = half * 64 + j * 8 + e;
                tmp.s[e] = T[s * 128 + ((cg ^ (s & 15)) << 3) + ce];
            }
            *(int4*)&vrow[j * 8] = tmp.v;
        }
    }
}

// ---------------------------------------------------------------------------
// Attention v3: QBLK=256, 8 waves (512 thr), grid 256 = 1 block/CU (perfect
// balance). Wave w owns q rows qt*256 + w*32 .. +31 and processes ALL 64 keys
// per tile (compute path = R5's correctness-validated v2 code verbatim).
// vs v1: 4x fewer chip-wide barrier-iterations (8192 vs 32768), 4x fewer K/V
// L2 re-reads, no cross-kh reduction epilogue.
// Staging: split across 8 waves, 2 gload16 each (waves 0-3: K strip w>>1,
// row-pair (w&1); waves 4-7: V strip (w-4)>>1, d-pair ((w-4)&1)); same
// swizzles/layout as v1. Tri-buffered + counted vmcnt (R7-validated):
// ledger (2 loads/wave/tile): prologue t0,t1 -> VMW(2) retires t0; iter tt
// issues t_{tt+2} into buf (tt+2)%3, VMW(2) retires t_{tt+1} (resident after
// the barrier: every wave's own share retired pre-barrier); tails VMW(0).
// WAR on buf (tt+2)%3 guarded by iter tt-1's closing barrier.
// LDS 48 KB. XCD map: bh=(id&7)+8*(id>>6) -> one bh's 8 q-blocks share an
// XCD (4 bh x 512KB = 2MB per L2).
// ---------------------------------------------------------------------------
__global__ __launch_bounds__(512, 2) void attn_kernel(
    const short* __restrict__ qws, const short* __restrict__ kws,
    const short* __restrict__ vperm, float* __restrict__ out)
{
    __shared__ short Kt[3][2][2048];   // [buf][kstrip][klocal*64 + dgrp_phys*8]
    __shared__ short Vt[3][2][2048];   // [buf][vstrip][d*32 + ug_phys*8]

    const int id = blockIdx.x;
    const int bh = (id & 7) + 8 * (id >> 6);       // same-bh blocks -> same XCD
    const int qt = (id >> 3) & 7;                  // 0..7
    const int b = bh >> 4, h = bh & (NH - 1);
    const size_t base = (size_t)bh * SEQ * HD;
    const int t = threadIdx.x, wave = t >> 6, lane = t & 63;
    const int quad = lane >> 4, l16 = lane & 15;

    // Q B-frags (q = qt*256 + wave*32 + qsub*16 + l16), loaded once
    bf16x8 bq[2][2];
#pragma unroll
    for (int qsub = 0; qsub < 2; ++qsub) {
        const short* qp = qws + base +
            (size_t)(qt * 256 + wave * 32 + qsub * 16 + l16) * HD + quad * 8;
        bq[qsub][0] = *(const bf16x8*)(qp);
        bq[qsub][1] = *(const bf16x8*)(qp + 32);
    }
    bf16x8 ones;
#pragma unroll
    for (int i = 0; i < 8; ++i) ones[i] = (short)0x3F80;

    // frag read offsets (shorts; (msub>>1) selects K strip, +2048)
    int koff[4][2];   // [msub][ks]: key = (msub>>1)*32 + (msub&1)*16 + l16, d = ks*32+quad*8
#pragma unroll
    for (int msub = 0; msub < 4; ++msub)
#pragma unroll
        for (int ks = 0; ks < 2; ++ks)
            koff[msub][ks] = (msub >> 1) * 2048 +
                ((msub & 1) * 16 + l16) * 64 + (((ks * 4 + quad) ^ (l16 & 7)) * 8);
    int voff[4];      // V B-frag: d=nt*16+l16, slot group = quad (phys ^ (d>>1)&3)
#pragma unroll
    for (int nt = 0; nt < 4; ++nt) {
        const int d = nt * 16 + l16;
        voff[nt] = d * 32 + ((quad ^ ((d >> 1) & 3)) * 8);
    }

    f32x4 o_acc[2][4] = {};   // [qsub][nt]
    f32x4 l_acc[2] = {};

    // stage tile tt into buffer p: 2 gload16 per wave (8 waves cover K+V)
    auto stage = [&](int tt, int p) {
        if (wave < 4) {   // K strip = wave>>1, row-pairs jj = (wave&1)*2 + {0,1}
            const int ks = wave >> 1;
#pragma unroll
            for (int j = 0; j < 2; ++j) {
                const int jj = (wave & 1) * 2 + j;
                const int kl = jj * 8 + (lane >> 3);
                const int row = tt * 64 + ks * 32 + kl;
                gload16(kws + base + (size_t)row * HD + (((lane & 7) ^ (kl & 7)) * 8),
                        &Kt[p][ks][jj * 512 + lane * 8]);
            }
        } else {          // V strip = (wave-4)>>1, d-pairs jj = ((wave-4)&1)*2 + {0,1}
            const int w = wave - 4, vs = w >> 1;
#pragma unroll
            for (int j = 0; j < 2; ++j) {
                const int jj = (w & 1) * 2 + j;
                const int d = jj * 16 + (lane >> 2);
                const int ug = (lane & 3) ^ ((d >> 1) & 3);
                gload16(vperm + base + (size_t)d * SEQ + tt * 64 + vs * 32 + ug * 8,
                        &Vt[p][vs][jj * 512 + lane * 8]);
            }
        }
    };

    // prologue: t0 -> buf0, t1 -> buf1; retire t0 only (t1 stays in flight)
    stage(0, 0);
    stage(1, 1);
    VMW(2);
    BARR();

    int p = 0, pn = 2;   // compute buffer / next stage buffer
#pragma unroll 1
    for (int tt = 0; tt < SEQ / 64; ++tt) {
        if (tt + 2 < SEQ / 64) stage(tt + 2, pn);
        const short* Kp = &Kt[p][0][0];
        const short* Vp = &Vt[p][0][0];

        // S^T: all 64 keys x this wave's 32 q
        f32x4 st[4][2];   // [msub][qsub]
#pragma unroll
        for (int msub = 0; msub < 4; ++msub) {
            bf16x8 a0 = *(const bf16x8*)(Kp + koff[msub][0]);
            bf16x8 a1 = *(const bf16x8*)(Kp + koff[msub][1]);
#pragma unroll
            for (int qsub = 0; qsub < 2; ++qsub) {
                f32x4 z = {};
                z = MFMA16(a0, bq[qsub][0], z);
                st[msub][qsub] = MFMA16(a1, bq[qsub][1], z);
            }
        }
        // per V-strip: exp + truncating pack -> P A-frag; l + O MFMAs
#pragma unroll
        for (int s = 0; s < 2; ++s) {
            bf16x8 vf[4];
#pragma unroll
            for (int nt = 0; nt < 4; ++nt)
                vf[nt] = *(const bf16x8*)(Vp + s * 2048 + voff[nt]);
#pragma unroll
            for (int qsub = 0; qsub < 2; ++qsub) {
                bf16x8 pa;
                unsigned* pu = (unsigned*)&pa;
                pu[0] = pack2bf_t(fast_exp2(st[2*s][qsub][0]), fast_exp2(st[2*s][qsub][1]));
                pu[1] = pack2bf_t(fast_exp2(st[2*s][qsub][2]), fast_exp2(st[2*s][qsub][3]));
                pu[2] = pack2bf_t(fast_exp2(st[2*s+1][qsub][0]), fast_exp2(st[2*s+1][qsub][1]));
                pu[3] = pack2bf_t(fast_exp2(st[2*s+1][qsub][2]), fast_exp2(st[2*s+1][qsub][3]));
                l_acc[qsub] = MFMA16(pa, ones, l_acc[qsub]);
#pragma unroll
                for (int nt = 0; nt < 4; ++nt)
                    o_acc[qsub][nt] = MFMA16(pa, vf[nt], o_acc[qsub][nt]);
            }
        }
        if (tt + 2 < SEQ / 64) { VMW(2); }   // retire t_{tt+1}; t_{tt+2} in flight
        else                   { VMW(0); }   // tail: drain
        BARR();
        p  = (p  == 2) ? 0 : p  + 1;
        pn = (pn == 2) ? 0 : pn + 1;
    }

    // ---- epilogue: o/l complete per wave -> direct store, no reduction ----
#pragma unroll
    for (int qsub = 0; qsub < 2; ++qsub) {
        float linv[4];
#pragma unroll
        for (int r = 0; r < 4; ++r)
            linv[r] = 1.0f / l_acc[qsub][r];
        const int s = qt * 256 + wave * 32 + qsub * 16 + quad * 4;
        float* ob = out + ((size_t)b * SEQ + s) * EMB + h * HD + l16;
#pragma unroll
        for (int nt = 0; nt < 4; ++nt)
#pragma unroll
            for (int r = 0; r < 4; ++r)
                ob[(size_t)r * EMB + nt * 16] = o_acc[qsub][nt][r] * linv[r];
    }
}

extern "C" void kernel_launch(void* const* d_in, const int* in_sizes, int n_in,
                              void* d_out, int out_size, void* d_ws, size_t ws_size,
                              hipStream_t stream) {
    (void)in_sizes; (void)n_in; (void)out_size; (void)ws_size;
    const float* x  = (const float*)d_in[0];
    const float* Wq = (const float*)d_in[1];
    const float* Wk = (const float*)d_in[2];
    const float* Wv = (const float*)d_in[3];
    const float* g  = (const float*)d_in[4];
    float* out = (float*)d_out;

    const size_t per = (size_t)BAT * NH * SEQ * HD;   // 4,194,304 elems
    short* qws   = (short*)d_ws;
    short* kws   = qws + per;
    short* vperm = kws + per;                          // ws: 25.2 MB total

    // bf16 staging lives in d_out (16.8 MB; attn fully overwrites it last)
    short* xb = (short*)out;                           // 4M shorts
    short* wb = xb + (size_t)MTOT * EMB;               // 3M shorts (7M <= 8.38M cap)

    prep_kernel<<<7168, 256, 0, stream>>>(x, Wq, Wk, Wv, xb, wb);
    qkv_gemm_fast<<<dim3(MTOT / 128, NTOT / 128), 256, 0, stream>>>(
        xb, wb, qws, kws, vperm, g);
    attn_kernel<<<(SEQ / 256) * BAT * NH, 512, 0, stream>>>(qws, kws, vperm, out);
}